// Round 1
// baseline (915.668 us; speedup 1.0000x reference)
//
#include <hip/hip_runtime.h>
#include <hip/hip_bf16.h>

#define T_TOK 16384
#define DIM   1024
#define HID   512
#define NEXP  64
#define BM    256
#define MAX_TILES 192

// meta layout (ints)
#define MW_CNT 0
#define MW_OFF 64
#define MW_CUR 192
#define MW_NT  256
#define MW_TE  320
#define MW_TR  (320 + MAX_TILES)
#define MW_TN  (320 + 2 * MAX_TILES)

typedef float f32x4 __attribute__((ext_vector_type(4)));
typedef short bf16x8 __attribute__((ext_vector_type(8)));
typedef short bf16x4 __attribute__((ext_vector_type(4)));

__device__ __forceinline__ unsigned short f2bf(float f) {
  union { float f; unsigned int u; } v; v.f = f;
  return (unsigned short)((v.u + 0x7FFFu + ((v.u >> 16) & 1u)) >> 16);
}

// ---------------- router: f32 logits GEMM + f64 top-4 refine + softmax ----------------
__global__ __launch_bounds__(256) void router_kernel(
    const float* __restrict__ x, const float* __restrict__ gw,
    int* __restrict__ meta, int* __restrict__ top_idx, float* __restrict__ top_score) {
  __shared__ float xs[64][68];   // [k][token]
  __shared__ float gs[64][68];   // [k][expert]
  __shared__ float ls[64][65];   // [token][expert]
  __shared__ float mz[64][2];
  __shared__ int cand[64][4];
  __shared__ double refd[64][4];

  const int tid = threadIdx.x;
  const int t0 = blockIdx.x * 64;
  const int tx = tid & 15, ty = tid >> 4;

  float acc[4][4];
#pragma unroll
  for (int i = 0; i < 4; ++i)
#pragma unroll
    for (int j = 0; j < 4; ++j) acc[i][j] = 0.f;

  for (int k0 = 0; k0 < DIM; k0 += 64) {
    __syncthreads();
#pragma unroll
    for (int p = 0; p < 4; ++p) {
      int r = ty + p * 16;
      int kc = tx * 4;
      f32x4 vx = *(const f32x4*)(x + (size_t)(t0 + r) * DIM + k0 + kc);
      f32x4 vg = *(const f32x4*)(gw + (size_t)r * DIM + k0 + kc);
#pragma unroll
      for (int j = 0; j < 4; ++j) { xs[kc + j][r] = vx[j]; gs[kc + j][r] = vg[j]; }
    }
    __syncthreads();
#pragma unroll 4
    for (int kk = 0; kk < 64; ++kk) {
      f32x4 a = *(const f32x4*)&xs[kk][ty * 4];
      f32x4 b = *(const f32x4*)&gs[kk][tx * 4];
#pragma unroll
      for (int i = 0; i < 4; ++i)
#pragma unroll
        for (int j = 0; j < 4; ++j)
          acc[i][j] = fmaf(a[i], b[j], acc[i][j]);
    }
  }
  __syncthreads();
#pragma unroll
  for (int i = 0; i < 4; ++i)
#pragma unroll
    for (int j = 0; j < 4; ++j)
      ls[ty * 4 + i][tx * 4 + j] = acc[i][j];
  __syncthreads();

  if (tid < 64) {
    float bv0 = -1e30f, bv1 = -1e30f, bv2 = -1e30f, bv3 = -1e30f;
    int bi0 = 0, bi1 = 0, bi2 = 0, bi3 = 0;
    for (int e = 0; e < 64; ++e) {
      float v = ls[tid][e];
      if (v > bv0)      { bv3=bv2; bi3=bi2; bv2=bv1; bi2=bi1; bv1=bv0; bi1=bi0; bv0=v; bi0=e; }
      else if (v > bv1) { bv3=bv2; bi3=bi2; bv2=bv1; bi2=bi1; bv1=v; bi1=e; }
      else if (v > bv2) { bv3=bv2; bi3=bi2; bv2=v; bi2=e; }
      else if (v > bv3) { bv3=v; bi3=e; }
    }
    float z = 0.f;
    for (int e = 0; e < 64; ++e) z += __expf(ls[tid][e] - bv0);
    mz[tid][0] = bv0; mz[tid][1] = z;
    cand[tid][0] = bi0; cand[tid][1] = bi1; cand[tid][2] = bi2; cand[tid][3] = bi3;
  }
  __syncthreads();
  {
    // f64 refinement of top-4 candidate logits (4 threads per token)
    int q = tid >> 2, c = tid & 3;
    int e = cand[q][c];
    const float* xr = x + (size_t)(t0 + q) * DIM;
    const float* gr = gw + (size_t)e * DIM;
    double ad = 0.0;
    for (int k = 0; k < DIM; k += 4) {
      f32x4 a = *(const f32x4*)(xr + k);
      f32x4 b = *(const f32x4*)(gr + k);
      ad += (double)a[0] * (double)b[0];
      ad += (double)a[1] * (double)b[1];
      ad += (double)a[2] * (double)b[2];
      ad += (double)a[3] * (double)b[3];
    }
    refd[q][c] = ad;
  }
  __syncthreads();
  if (tid < 64) {
    int t = t0 + tid;
    double dv[4]; int di[4];
#pragma unroll
    for (int c = 0; c < 4; ++c) { dv[c] = refd[tid][c]; di[c] = cand[tid][c]; }
    int o0 = 0;
#pragma unroll
    for (int c = 1; c < 4; ++c)
      if (dv[c] > dv[o0] || (dv[c] == dv[o0] && di[c] < di[o0])) o0 = c;
    int o1 = -1;
#pragma unroll
    for (int c = 0; c < 4; ++c) {
      if (c == o0) continue;
      if (o1 < 0 || dv[c] > dv[o1] || (dv[c] == dv[o1] && di[c] < di[o1])) o1 = c;
    }
    int e0 = di[o0], e1 = di[o1];
    float m = mz[tid][0], z = mz[tid][1];
    float s0 = __expf(ls[tid][e0] - m) / z;
    float s1 = __expf(ls[tid][e1] - m) / z;
    top_idx[t * 2] = e0; top_idx[t * 2 + 1] = e1;
    top_score[t * 2] = s0; top_score[t * 2 + 1] = s1;
    atomicAdd(&meta[MW_CNT + e0], 1);
    atomicAdd(&meta[MW_CNT + e1], 1);
  }
}

// ---------------- prefix sum + tile table (serial, tiny) ----------------
__global__ void scan_kernel(int* meta) {
  if (threadIdx.x != 0 || blockIdx.x != 0) return;
  int off = 0, nt = 0;
  for (int e = 0; e < NEXP; ++e) {
    int c = meta[MW_CNT + e];
    meta[MW_OFF + e] = off;
    meta[MW_CUR + e] = off;
    int tiles = (c + BM - 1) / BM;
    for (int i = 0; i < tiles; ++i) {
      meta[MW_TE + nt] = e;
      meta[MW_TR + nt] = off + i * BM;
      meta[MW_TN + nt] = min(BM, c - i * BM);
      ++nt;
    }
    off += c;
  }
  meta[MW_OFF + NEXP] = off;
  meta[MW_NT] = nt;
}

// ---------------- scatter tokens into expert-contiguous order ----------------
__global__ __launch_bounds__(256) void scatter_kernel(
    const int* __restrict__ top_idx, int* __restrict__ meta,
    int* __restrict__ tok_perm, int* __restrict__ outrow_perm) {
  int t = blockIdx.x * 256 + threadIdx.x;
#pragma unroll
  for (int s = 0; s < 2; ++s) {
    int e = top_idx[t * 2 + s];
    int p = atomicAdd(&meta[MW_CUR + e], 1);
    tok_perm[p] = t;
    outrow_perm[p] = t * 2 + s;
  }
}

// ---------------- GEMM1: H = silu(X W1^T) * (X W3^T), bf16 MFMA ----------------
__global__ __launch_bounds__(512) void gemm1_kernel(
    const float* __restrict__ x, const float* __restrict__ w1, const float* __restrict__ w3,
    const int* __restrict__ meta, const int* __restrict__ tok_perm,
    unsigned short* __restrict__ Hbuf) {
  const int tile = blockIdx.x;
  if (tile >= meta[MW_NT]) return;
  const int e = meta[MW_TE + tile];
  const int row0 = meta[MW_TR + tile];
  const int nrows = meta[MW_TN + tile];
  const int n0 = blockIdx.y * 128;

  __shared__ __align__(16) unsigned short As[256][72];
  __shared__ __align__(16) unsigned short B1s[128][72];
  __shared__ __align__(16) unsigned short B3s[128][72];

  const int tid = threadIdx.x;
  const int wid = tid >> 6, lane = tid & 63;
  const int wr = wid >> 1, wc = wid & 1;
  const int lrow = lane & 15, khalf = lane >> 4;

  const int sr = tid >> 4;            // staging row base
  const int skc = (tid & 15) * 4;     // staging k offset

  int tkr[8];
#pragma unroll
  for (int p = 0; p < 8; ++p) {
    int r = sr + p * 32;
    tkr[p] = tok_perm[row0 + min(r, nrows - 1)];
  }
  const float* w1b = w1 + ((size_t)e * HID + n0) * DIM;
  const float* w3b = w3 + ((size_t)e * HID + n0) * DIM;

  f32x4 acc1[4][4], acc3[4][4];
  const f32x4 vz = {0.f, 0.f, 0.f, 0.f};
#pragma unroll
  for (int i = 0; i < 4; ++i)
#pragma unroll
    for (int j = 0; j < 4; ++j) { acc1[i][j] = vz; acc3[i][j] = vz; }

  for (int k0 = 0; k0 < DIM; k0 += 64) {
    __syncthreads();
#pragma unroll
    for (int p = 0; p < 8; ++p) {
      int r = sr + p * 32;
      f32x4 v = *(const f32x4*)(x + (size_t)tkr[p] * DIM + k0 + skc);
      bf16x4 pk;
#pragma unroll
      for (int j = 0; j < 4; ++j) pk[j] = (short)f2bf(v[j]);
      *(bf16x4*)&As[r][skc] = pk;
    }
#pragma unroll
    for (int p = 0; p < 4; ++p) {
      int r = sr + p * 32;
      f32x4 v1 = *(const f32x4*)(w1b + (size_t)r * DIM + k0 + skc);
      f32x4 v3 = *(const f32x4*)(w3b + (size_t)r * DIM + k0 + skc);
      bf16x4 p1, p3;
#pragma unroll
      for (int j = 0; j < 4; ++j) { p1[j] = (short)f2bf(v1[j]); p3[j] = (short)f2bf(v3[j]); }
      *(bf16x4*)&B1s[r][skc] = p1;
      *(bf16x4*)&B3s[r][skc] = p3;
    }
    __syncthreads();
#pragma unroll
    for (int kk = 0; kk < 64; kk += 32) {
      const int kf = kk + khalf * 8;
      bf16x8 a[4], b1[4], b3[4];
#pragma unroll
      for (int mf = 0; mf < 4; ++mf)
        a[mf] = *(const bf16x8*)&As[wr * 64 + mf * 16 + lrow][kf];
#pragma unroll
      for (int nf = 0; nf < 4; ++nf) {
        b1[nf] = *(const bf16x8*)&B1s[wc * 64 + nf * 16 + lrow][kf];
        b3[nf] = *(const bf16x8*)&B3s[wc * 64 + nf * 16 + lrow][kf];
      }
#pragma unroll
      for (int mf = 0; mf < 4; ++mf)
#pragma unroll
        for (int nf = 0; nf < 4; ++nf) {
          acc1[mf][nf] = __builtin_amdgcn_mfma_f32_16x16x32_bf16(a[mf], b1[nf], acc1[mf][nf], 0, 0, 0);
          acc3[mf][nf] = __builtin_amdgcn_mfma_f32_16x16x32_bf16(a[mf], b3[nf], acc3[mf][nf], 0, 0, 0);
        }
    }
  }
#pragma unroll
  for (int mf = 0; mf < 4; ++mf)
#pragma unroll
    for (int nf = 0; nf < 4; ++nf)
#pragma unroll
      for (int r = 0; r < 4; ++r) {
        int row = wr * 64 + mf * 16 + khalf * 4 + r;
        if (row < nrows) {
          float v1 = acc1[mf][nf][r];
          float v3 = acc3[mf][nf][r];
          float h = v1 / (1.f + __expf(-v1)) * v3;
          int col = n0 + wc * 64 + nf * 16 + lrow;
          Hbuf[(size_t)(row0 + row) * HID + col] = f2bf(h);
        }
      }
}

// ---------------- GEMM2: OUT = H W2^T, write to (token,slot)-indexed f32 buffer ----------------
__global__ __launch_bounds__(512) void gemm2_kernel(
    const unsigned short* __restrict__ Hbuf, const float* __restrict__ w2,
    const int* __restrict__ meta, const int* __restrict__ outrow_perm,
    float* __restrict__ outbuf) {
  const int tile = blockIdx.x;
  if (tile >= meta[MW_NT]) return;
  const int e = meta[MW_TE + tile];
  const int row0 = meta[MW_TR + tile];
  const int nrows = meta[MW_TN + tile];
  const int n0 = blockIdx.y * 128;

  __shared__ __align__(16) unsigned short As[256][72];
  __shared__ __align__(16) unsigned short Bs[128][72];

  const int tid = threadIdx.x;
  const int wid = tid >> 6, lane = tid & 63;
  const int wr = wid >> 1, wc = wid & 1;
  const int lrow = lane & 15, khalf = lane >> 4;

  const int sr8 = tid >> 3;          // 0..63  (A bf16 staging, 16B chunks)
  const int skc8 = (tid & 7) * 8;
  const int sr = tid >> 4;           // 0..31  (B f32 staging)
  const int skc = (tid & 15) * 4;

  const float* w2b = w2 + ((size_t)e * DIM + n0) * HID;

  f32x4 acc[4][4];
  const f32x4 vz = {0.f, 0.f, 0.f, 0.f};
#pragma unroll
  for (int i = 0; i < 4; ++i)
#pragma unroll
    for (int j = 0; j < 4; ++j) acc[i][j] = vz;

  for (int k0 = 0; k0 < HID; k0 += 64) {
    __syncthreads();
#pragma unroll
    for (int p = 0; p < 4; ++p) {
      int r = sr8 + p * 64;
      int rr = min(r, nrows - 1);
      bf16x8 v = *(const bf16x8*)(Hbuf + (size_t)(row0 + rr) * HID + k0 + skc8);
      *(bf16x8*)&As[r][skc8] = v;
    }
#pragma unroll
    for (int p = 0; p < 4; ++p) {
      int r = sr + p * 32;
      f32x4 v = *(const f32x4*)(w2b + (size_t)r * HID + k0 + skc);
      bf16x4 pk;
#pragma unroll
      for (int j = 0; j < 4; ++j) pk[j] = (short)f2bf(v[j]);
      *(bf16x4*)&Bs[r][skc] = pk;
    }
    __syncthreads();
#pragma unroll
    for (int kk = 0; kk < 64; kk += 32) {
      const int kf = kk + khalf * 8;
      bf16x8 a[4], b[4];
#pragma unroll
      for (int mf = 0; mf < 4; ++mf)
        a[mf] = *(const bf16x8*)&As[wr * 64 + mf * 16 + lrow][kf];
#pragma unroll
      for (int nf = 0; nf < 4; ++nf)
        b[nf] = *(const bf16x8*)&Bs[wc * 64 + nf * 16 + lrow][kf];
#pragma unroll
      for (int mf = 0; mf < 4; ++mf)
#pragma unroll
        for (int nf = 0; nf < 4; ++nf)
          acc[mf][nf] = __builtin_amdgcn_mfma_f32_16x16x32_bf16(a[mf], b[nf], acc[mf][nf], 0, 0, 0);
    }
  }
#pragma unroll
  for (int mf = 0; mf < 4; ++mf)
#pragma unroll
    for (int nf = 0; nf < 4; ++nf)
#pragma unroll
      for (int r = 0; r < 4; ++r) {
        int row = wr * 64 + mf * 16 + khalf * 4 + r;
        if (row < nrows) {
          int p = row0 + row;
          int orow = outrow_perm[p];
          int col = n0 + wc * 64 + nf * 16 + lrow;
          outbuf[(size_t)orow * DIM + col] = acc[mf][nf][r];
        }
      }
}

// ---------------- combine: y[t] = s0*out[2t] + s1*out[2t+1] ----------------
__global__ __launch_bounds__(256) void combine_kernel(
    const float* __restrict__ outbuf, const float* __restrict__ top_score,
    float* __restrict__ y) {
  size_t gid = (size_t)blockIdx.x * 256 + threadIdx.x;
  size_t i = gid * 4;
  int t = (int)(i >> 10);
  int d = (int)(i & 1023);
  float s0 = top_score[t * 2], s1 = top_score[t * 2 + 1];
  f32x4 o0 = *(const f32x4*)(outbuf + ((size_t)(t * 2) << 10) + d);
  f32x4 o1 = *(const f32x4*)(outbuf + ((size_t)(t * 2 + 1) << 10) + d);
  f32x4 r;
#pragma unroll
  for (int j = 0; j < 4; ++j) r[j] = fmaf(s1, o1[j], s0 * o0[j]);
  *(f32x4*)(y + i) = r;
}

extern "C" void kernel_launch(void* const* d_in, const int* in_sizes, int n_in,
                              void* d_out, int out_size, void* d_ws, size_t ws_size,
                              hipStream_t stream) {
  const float* x  = (const float*)d_in[0];
  const float* gw = (const float*)d_in[1];
  const float* w1 = (const float*)d_in[2];
  const float* w2 = (const float*)d_in[3];
  const float* w3 = (const float*)d_in[4];
  float* y = (float*)d_out;

  char* ws = (char*)d_ws;
  int* meta            = (int*)ws;                       // 4 KB
  int* top_idx         = (int*)(ws + 8192);              // 128 KB
  float* top_score     = (float*)(ws + 139264);          // 128 KB
  int* tok_perm        = (int*)(ws + 270336);            // 128 KB
  int* outrow_perm     = (int*)(ws + 401408);            // 128 KB
  unsigned short* Hbuf = (unsigned short*)(ws + (1u << 20));    // 32 MB bf16
  float* outbuf        = (float*)(ws + (36u << 20));            // 128 MB f32

  hipMemsetAsync(meta, 0, 4096, stream);
  router_kernel<<<T_TOK / 64, 256, 0, stream>>>(x, gw, meta, top_idx, top_score);
  scan_kernel<<<1, 64, 0, stream>>>(meta);
  scatter_kernel<<<T_TOK / 256, 256, 0, stream>>>(top_idx, meta, tok_perm, outrow_perm);
  gemm1_kernel<<<dim3(MAX_TILES, 4), 512, 0, stream>>>(x, w1, w3, meta, tok_perm, Hbuf);
  gemm2_kernel<<<dim3(MAX_TILES, 8), 512, 0, stream>>>(Hbuf, w2, meta, outrow_perm, outbuf);
  combine_kernel<<<(T_TOK * DIM / 4) / 256, 256, 0, stream>>>(outbuf, top_score, y);
}